// Round 8
// baseline (240.989 us; speedup 1.0000x reference)
//
#include <hip/hip_runtime.h>

// Problem constants (fixed by setup_inputs): B=32, C=256, H=W=64
#define BATCH 32
#define CHAN  256
#define HGT   64
#define WID   64
#define HW    4096   // HGT*WID
#define CPB   8      // channels per block == waves per block (512 threads)

// Fused v4: 512-thread blocks, TWO resident blocks per CU.
//   Same software-pipelined structure as v3 (issue offsets, then ALL 16 data
//   float4 loads, scatter the weight map under the loads' flight, barrier,
//   drain against LDS) -- but with 2 co-resident unsynchronized blocks per CU,
//   one block's memory-idle drain/teardown phase overlaps the other block's
//   16-deep stream. Memory stays busy through the barrier drains that a
//   single resident block serializes on.
//   grid = 32 batches x 32 groups = 1024 blocks; launch_bounds(512,4)
//   caps VGPR at 128 (est ~100) -> 4 waves/SIMD = 2 blocks/CU.
__global__ __launch_bounds__(512, 4) void fused_bilinear_pool(
        const float* __restrict__ data,     // [B, C, H, W] fp32
        const float* __restrict__ offset,   // [B, 2, H, W] fp32
        const float* __restrict__ ts_ptr,   // scalar fp32
        float* __restrict__ out)            // [B, C] fp32
{
    const int blk  = blockIdx.x;            // 0..1023
    const int b    = blk >> 5;              // 32 groups per batch
    const int g    = blk & 31;              // channel group within batch
    const int tid  = threadIdx.x;           // 0..511
    const int w    = tid >> 6;              // wave id = channel within group
    const int lane = tid & 63;

    __shared__ float acc[HW];               // 16 KiB weight map

    // ---- zero the map; barrier with no vmem outstanding ----
    #pragma unroll
    for (int z = 0; z < 8; ++z) acc[tid + z * 512] = 0.0f;
    __syncthreads();

    // ---- issue offset loads FIRST (oldest vmem ops) ----
    // thread covers 8 consecutive points p = 8*tid .. 8*tid+7 (same row)
    const float* off_y = offset + (size_t)b * 2 * HW;   // offset[b,0]
    const float* off_x = off_y + HW;                    // offset[b,1]
    const float4 dy4a = *reinterpret_cast<const float4*>(off_y + tid * 8);
    const float4 dy4b = *reinterpret_cast<const float4*>(off_y + tid * 8 + 4);
    const float4 dx4a = *reinterpret_cast<const float4*>(off_x + tid * 8);
    const float4 dx4b = *reinterpret_cast<const float4*>(off_x + tid * 8 + 4);

    // ---- issue ALL 16 data loads (in flight through the scatter) ----
    const float* plane = data + ((size_t)(b * CHAN + g * CPB + w)) * HW;
    float4 d[16];
    #pragma unroll
    for (int s = 0; s < 16; ++s)
        d[s] = *reinterpret_cast<const float4*>(plane + s * 256 + lane * 4);

    float ts = ts_ptr[0];
    ts = fminf(fmaxf(ts, 0.001f), 0.01f);

    // ---- Phase A: scatter 8 contiguous points per thread ----
    {
        const int i  = tid >> 3;            // (8*tid) >> 6
        const int j0 = (tid & 7) * 8;
        const float dys[8] = {dy4a.x, dy4a.y, dy4a.z, dy4a.w,
                              dy4b.x, dy4b.y, dy4b.z, dy4b.w};
        const float dxs[8] = {dx4a.x, dx4a.y, dx4a.z, dx4a.w,
                              dx4b.x, dx4b.y, dx4b.z, dx4b.w};
        #pragma unroll
        for (int e = 0; e < 8; ++e) {
            // reference eval order: clip(i + (ts*offset)*H, 0, H-1)
            float y = fminf(fmaxf((float)i        + ts * dys[e] * 64.0f, 0.0f), 63.0f);
            float x = fminf(fmaxf((float)(j0 + e) + ts * dxs[e] * 64.0f, 0.0f), 63.0f);
            int y0 = (int)floorf(y); y0 = min(max(y0, 0), HGT - 2);
            int x0 = (int)floorf(x); x0 = min(max(x0, 0), WID - 2);
            const float wy = y - (float)y0;
            const float wx = x - (float)x0;
            const int base = (y0 << 6) + x0;
            atomicAdd(&acc[base],           (1.0f - wy) * (1.0f - wx));
            atomicAdd(&acc[base + 1],       (1.0f - wy) * wx);
            atomicAdd(&acc[base + WID],     wy * (1.0f - wx));
            atomicAdd(&acc[base + WID + 1], wy * wx);
        }
    }
    __syncthreads();   // vmcnt drain -- data arrived during the scatter

    // ---- Phase B: drain 16 registered float4 against the LDS map ----
    float a0 = 0.0f, a1 = 0.0f, a2 = 0.0f, a3 = 0.0f;
    #pragma unroll
    for (int s = 0; s < 16; ++s) {
        const float4 av =
            *reinterpret_cast<const float4*>(acc + s * 256 + lane * 4);
        if ((s & 3) == 0) {
            a0 = fmaf(av.x, d[s].x, a0); a0 = fmaf(av.y, d[s].y, a0);
            a0 = fmaf(av.z, d[s].z, a0); a0 = fmaf(av.w, d[s].w, a0);
        } else if ((s & 3) == 1) {
            a1 = fmaf(av.x, d[s].x, a1); a1 = fmaf(av.y, d[s].y, a1);
            a1 = fmaf(av.z, d[s].z, a1); a1 = fmaf(av.w, d[s].w, a1);
        } else if ((s & 3) == 2) {
            a2 = fmaf(av.x, d[s].x, a2); a2 = fmaf(av.y, d[s].y, a2);
            a2 = fmaf(av.z, d[s].z, a2); a2 = fmaf(av.w, d[s].w, a2);
        } else {
            a3 = fmaf(av.x, d[s].x, a3); a3 = fmaf(av.y, d[s].y, a3);
            a3 = fmaf(av.z, d[s].z, a3); a3 = fmaf(av.w, d[s].w, a3);
        }
    }
    float sum = (a0 + a1) + (a2 + a3);

    // ---- wave-64 register-only shuffle reduce; no further barriers ----
    #pragma unroll
    for (int off = 32; off > 0; off >>= 1)
        sum += __shfl_down(sum, off, 64);

    if (lane == 0)
        out[(b << 8) + g * CPB + w] = sum * (1.0f / (float)HW);  // fold mean
}

extern "C" void kernel_launch(void* const* d_in, const int* in_sizes, int n_in,
                              void* d_out, int out_size, void* d_ws, size_t ws_size,
                              hipStream_t stream) {
    const float* data   = (const float*)d_in[0];  // fp32 [32,256,64,64]
    const float* offset = (const float*)d_in[1];  // fp32 [32,2,64,64]
    const float* ts     = (const float*)d_in[2];  // fp32 scalar

    float* out = (float*)d_out;                   // [32, 256] fp32
    (void)d_ws; (void)ws_size;                    // workspace intentionally unused

    fused_bilinear_pool<<<BATCH * 32, 512, 0, stream>>>(data, offset, ts, out);
}

// Round 9
// 214.863 us; speedup vs baseline: 1.1216x; 1.1216x over previous
//
#include <hip/hip_runtime.h>
#include <stdint.h>

// Problem constants (fixed by setup_inputs): B=32, C=256, H=W=64
#define BATCH 32
#define CHAN  256
#define HGT   64
#define WID   64
#define HW    4096   // HGT*WID
#define GPB   8      // blocks per batch  -> grid = 256 = 1 block/CU
#define CPB   32     // channels per block (2 per wave)

typedef float v4f __attribute__((ext_vector_type(4)));

// 8 pinned 16B loads = half a plane per wave (2048 floats).
// asm volatile: compiler cannot sink/split these (R8 post-mortem: C-level
// loads were sunk past the barrier, VGPR 48, pipeline destroyed).
// offset: immediates are BYTES, max 4095 -> two base operands 4096 B apart.
#define GLOAD8(B0,B1,B2,B3,B4,B5,B6,B7, P0, P1)                       \
    asm volatile(                                                      \
        "global_load_dwordx4 %0, %8, off\n\t"                          \
        "global_load_dwordx4 %1, %8, off offset:1024\n\t"              \
        "global_load_dwordx4 %2, %8, off offset:2048\n\t"              \
        "global_load_dwordx4 %3, %8, off offset:3072\n\t"              \
        "global_load_dwordx4 %4, %9, off\n\t"                          \
        "global_load_dwordx4 %5, %9, off offset:1024\n\t"              \
        "global_load_dwordx4 %6, %9, off offset:2048\n\t"              \
        "global_load_dwordx4 %7, %9, off offset:3072"                  \
        : "=&v"(B0), "=&v"(B1), "=&v"(B2), "=&v"(B3),                  \
          "=&v"(B4), "=&v"(B5), "=&v"(B6), "=&v"(B7)                   \
        : "v"(P0), "v"(P1)                                             \
        : "memory")

// counted wait (compiler doesn't know the asm loads exist -> manual vmcnt);
// sched_barrier(0) right after so dependent FMAs can't hoist above (rule #18)
#define WAITVM(N)                                                      \
    asm volatile("s_waitcnt vmcnt(" #N ")" ::: "memory");              \
    __builtin_amdgcn_sched_barrier(0)

#define FMA4(S, AV, DV)                                                \
    S = fmaf((AV).x, (DV).x, S); S = fmaf((AV).y, (DV).y, S);          \
    S = fmaf((AV).z, (DV).z, S); S = fmaf((AV).w, (DV).w, S)

// drain one half-plane buffer against the matching LDS map half
#define DRAIN8(B0,B1,B2,B3,B4,B5,B6,B7, HP, S0,S1,S2,S3)               \
    { const float4 a0_ = *reinterpret_cast<const float4*>((HP) + 0*256); FMA4(S0, a0_, B0); \
      const float4 a1_ = *reinterpret_cast<const float4*>((HP) + 1*256); FMA4(S1, a1_, B1); \
      const float4 a2_ = *reinterpret_cast<const float4*>((HP) + 2*256); FMA4(S2, a2_, B2); \
      const float4 a3_ = *reinterpret_cast<const float4*>((HP) + 3*256); FMA4(S3, a3_, B3); \
      const float4 a4_ = *reinterpret_cast<const float4*>((HP) + 4*256); FMA4(S0, a4_, B4); \
      const float4 a5_ = *reinterpret_cast<const float4*>((HP) + 5*256); FMA4(S1, a5_, B5); \
      const float4 a6_ = *reinterpret_cast<const float4*>((HP) + 6*256); FMA4(S2, a6_, B6); \
      const float4 a7_ = *reinterpret_cast<const float4*>((HP) + 7*256); FMA4(S3, a7_, B7); }

// Fused v5: 256 persistent 1024-thread blocks (1/CU, no tail).
//   Per block: build the batch's weight map in LDS once (scatter, 1 barrier),
//   then each wave independently streams TWO planes through a register-
//   resident double-buffered ring of inline-asm loads with counted vmcnt(8)
//   -- continuous 16-deep stream, no barriers, no burst-then-drain gaps.
//   No asm load is outstanding across any __syncthreads.
__global__ __launch_bounds__(1024) void fused_bilinear_pool(
        const float* __restrict__ data,     // [B, C, H, W] fp32
        const float* __restrict__ offset,   // [B, 2, H, W] fp32
        const float* __restrict__ ts_ptr,   // scalar fp32
        float* __restrict__ out)            // [B, C] fp32
{
    const int blk  = blockIdx.x;            // 0..255
    const int b    = blk >> 3;              // 8 blocks per batch
    const int g    = blk & 7;               // channel group (32 ch) in batch
    const int tid  = threadIdx.x;
    const int w    = tid >> 6;              // wave id 0..15
    const int lane = tid & 63;

    __shared__ float acc[HW];               // 16 KiB weight map

    // ---- zero the map ----
    acc[tid]        = 0.0f;
    acc[tid + 1024] = 0.0f;
    acc[tid + 2048] = 0.0f;
    acc[tid + 3072] = 0.0f;
    __syncthreads();

    // ---- offsets + scatter (4 contiguous points per thread, once/block) ----
    const float* off_y = offset + (size_t)b * 2 * HW;   // offset[b,0]
    const float* off_x = off_y + HW;                    // offset[b,1]
    const float4 dy4 = *reinterpret_cast<const float4*>(off_y + tid * 4);
    const float4 dx4 = *reinterpret_cast<const float4*>(off_x + tid * 4);

    float ts = ts_ptr[0];
    ts = fminf(fmaxf(ts, 0.001f), 0.01f);

    {
        const int i  = tid >> 4;            // (4*tid) >> 6
        const int j0 = (tid << 2) & 63;
        const float dys[4] = {dy4.x, dy4.y, dy4.z, dy4.w};
        const float dxs[4] = {dx4.x, dx4.y, dx4.z, dx4.w};
        #pragma unroll
        for (int e = 0; e < 4; ++e) {
            // reference eval order: clip(i + (ts*offset)*H, 0, H-1)
            float y = fminf(fmaxf((float)i        + ts * dys[e] * 64.0f, 0.0f), 63.0f);
            float x = fminf(fmaxf((float)(j0 + e) + ts * dxs[e] * 64.0f, 0.0f), 63.0f);
            int y0 = (int)floorf(y); y0 = min(max(y0, 0), HGT - 2);
            int x0 = (int)floorf(x); x0 = min(max(x0, 0), WID - 2);
            const float wy = y - (float)y0;
            const float wx = x - (float)x0;
            const int base = (y0 << 6) + x0;
            atomicAdd(&acc[base],           (1.0f - wy) * (1.0f - wx));
            atomicAdd(&acc[base + 1],       (1.0f - wy) * wx);
            atomicAdd(&acc[base + WID],     wy * (1.0f - wx));
            atomicAdd(&acc[base + WID + 1], wy * wx);
        }
    }
    __syncthreads();   // map ready; no asm loads outstanding here

    // ---- per-wave barrier-free stream of 2 planes (c0+w, c0+w+16) ----
    const int c0 = g * CPB;
    const float* p0 = data + ((size_t)b * CHAN + c0 + w) * HW + lane * 4;
    const float* p1 = p0 + 16 * HW;         // second plane for this wave

    const float* hp0 = acc + lane * 4;          // map half 0
    const float* hp1 = acc + 2048 + lane * 4;   // map half 1

    v4f A0,A1,A2,A3,A4,A5,A6,A7;
    v4f B0,B1,B2,B3,B4,B5,B6,B7;

    GLOAD8(A0,A1,A2,A3,A4,A5,A6,A7, p0,        p0 + 1024);  // plane0 half0
    GLOAD8(B0,B1,B2,B3,B4,B5,B6,B7, p0 + 2048, p0 + 3072);  // plane0 half1

    float s0=0.f,s1=0.f,s2=0.f,s3=0.f;   // plane 0
    float t0=0.f,t1=0.f,t2=0.f,t3=0.f;   // plane 1

    WAITVM(8);                                               // A(p0h0) ready
    DRAIN8(A0,A1,A2,A3,A4,A5,A6,A7, hp0, s0,s1,s2,s3);
    GLOAD8(A0,A1,A2,A3,A4,A5,A6,A7, p1,        p1 + 1024);   // plane1 half0

    WAITVM(8);                                               // B(p0h1) ready
    DRAIN8(B0,B1,B2,B3,B4,B5,B6,B7, hp1, s0,s1,s2,s3);
    GLOAD8(B0,B1,B2,B3,B4,B5,B6,B7, p1 + 2048, p1 + 3072);   // plane1 half1

    WAITVM(8);                                               // A(p1h0) ready
    DRAIN8(A0,A1,A2,A3,A4,A5,A6,A7, hp0, t0,t1,t2,t3);

    WAITVM(0);                                               // B(p1h1) ready
    DRAIN8(B0,B1,B2,B3,B4,B5,B6,B7, hp1, t0,t1,t2,t3);

    float sum0 = (s0 + s1) + (s2 + s3);
    float sum1 = (t0 + t1) + (t2 + t3);

    // wave-64 register-only shuffle reduce (two independent chains)
    #pragma unroll
    for (int off = 32; off > 0; off >>= 1) {
        sum0 += __shfl_down(sum0, off, 64);
        sum1 += __shfl_down(sum1, off, 64);
    }

    if (lane == 0) {
        const float s = 1.0f / (float)HW;   // fold the mean
        out[(b << 8) + c0 + w]      = sum0 * s;
        out[(b << 8) + c0 + w + 16] = sum1 * s;
    }
}

extern "C" void kernel_launch(void* const* d_in, const int* in_sizes, int n_in,
                              void* d_out, int out_size, void* d_ws, size_t ws_size,
                              hipStream_t stream) {
    const float* data   = (const float*)d_in[0];  // fp32 [32,256,64,64]
    const float* offset = (const float*)d_in[1];  // fp32 [32,2,64,64]
    const float* ts     = (const float*)d_in[2];  // fp32 scalar

    float* out = (float*)d_out;                   // [32, 256] fp32
    (void)d_ws; (void)ws_size;                    // workspace intentionally unused

    fused_bilinear_pool<<<BATCH * GPB, 1024, 0, stream>>>(data, offset, ts, out);
}

// Round 10
// 202.605 us; speedup vs baseline: 1.1895x; 1.0605x over previous
//
#include <hip/hip_runtime.h>
#include <stdint.h>

// Problem constants (fixed by setup_inputs): B=32, C=256, H=W=64
#define BATCH 32
#define CHAN  256
#define HGT   64
#define WID   64
#define HW    4096   // HGT*WID
#define GPB   8      // blocks per batch  -> grid = 256 = exactly 1 block/CU
#define CPB   32     // channels per block (4 per wave)

typedef float v4f __attribute__((ext_vector_type(4)));

// 8 pinned 16B loads = half a plane per wave. asm volatile: compiler cannot
// sink/split/shrink (R5/R8 post-mortem: C-level loads sunk, VGPR 32-48,
// pipeline destroyed). offset: immediates are BYTES <=4095 -> 2 bases 4KB apart.
#define GLOAD8(B0,B1,B2,B3,B4,B5,B6,B7, P0, P1)                       \
    asm volatile(                                                      \
        "global_load_dwordx4 %0, %8, off\n\t"                          \
        "global_load_dwordx4 %1, %8, off offset:1024\n\t"              \
        "global_load_dwordx4 %2, %8, off offset:2048\n\t"              \
        "global_load_dwordx4 %3, %8, off offset:3072\n\t"              \
        "global_load_dwordx4 %4, %9, off\n\t"                          \
        "global_load_dwordx4 %5, %9, off offset:1024\n\t"              \
        "global_load_dwordx4 %6, %9, off offset:2048\n\t"              \
        "global_load_dwordx4 %7, %9, off offset:3072"                  \
        : "=&v"(B0), "=&v"(B1), "=&v"(B2), "=&v"(B3),                  \
          "=&v"(B4), "=&v"(B5), "=&v"(B6), "=&v"(B7)                   \
        : "v"(P0), "v"(P1)                                             \
        : "memory")

// full-plane issue: 16 loads into a 16-buffer set
#define GLOADP(R, P)                                                   \
    GLOAD8(R##0,R##1,R##2,R##3,R##4,R##5,R##6,R##7, (P), (P) + 1024);  \
    GLOAD8(R##8,R##9,R##10,R##11,R##12,R##13,R##14,R##15,              \
           (P) + 2048, (P) + 3072)

// counted wait; sched_barrier(0) so dependent FMAs can't hoist above (rule #18)
#define WAITVM(N)                                                      \
    asm volatile("s_waitcnt vmcnt(" #N ")" ::: "memory");              \
    __builtin_amdgcn_sched_barrier(0)

#define FMA4(S, AV, DV)                                                \
    S = fmaf((AV).x, (DV).x, S); S = fmaf((AV).y, (DV).y, S);          \
    S = fmaf((AV).z, (DV).z, S); S = fmaf((AV).w, (DV).w, S)

#define DRAIN8(B0,B1,B2,B3,B4,B5,B6,B7, HP, S0,S1,S2,S3)               \
    { const float4 a0_ = *reinterpret_cast<const float4*>((HP) + 0*256); FMA4(S0, a0_, B0); \
      const float4 a1_ = *reinterpret_cast<const float4*>((HP) + 1*256); FMA4(S1, a1_, B1); \
      const float4 a2_ = *reinterpret_cast<const float4*>((HP) + 2*256); FMA4(S2, a2_, B2); \
      const float4 a3_ = *reinterpret_cast<const float4*>((HP) + 3*256); FMA4(S3, a3_, B3); \
      const float4 a4_ = *reinterpret_cast<const float4*>((HP) + 4*256); FMA4(S0, a4_, B4); \
      const float4 a5_ = *reinterpret_cast<const float4*>((HP) + 5*256); FMA4(S1, a5_, B5); \
      const float4 a6_ = *reinterpret_cast<const float4*>((HP) + 6*256); FMA4(S2, a6_, B6); \
      const float4 a7_ = *reinterpret_cast<const float4*>((HP) + 7*256); FMA4(S3, a7_, B7); }

// drain a full 16-buffer plane set against the whole LDS map + reduce to 1 float
#define DRAINP(R, HP0, HP1, OUTF)                                      \
    { float s0_=0.f,s1_=0.f,s2_=0.f,s3_=0.f;                           \
      DRAIN8(R##0,R##1,R##2,R##3,R##4,R##5,R##6,R##7, HP0, s0_,s1_,s2_,s3_); \
      DRAIN8(R##8,R##9,R##10,R##11,R##12,R##13,R##14,R##15, HP1, s0_,s1_,s2_,s3_); \
      OUTF = (s0_ + s1_) + (s2_ + s3_); }

// Fused v6 = R7's issue-under-scatter + R9's pinned ring, persistent.
//   256 blocks (1/CU, no tail), 512 threads (8 waves), 4 planes/wave.
//   t=0: ts load; asm-pin 4 offset loads then 16 data loads (plane P0);
//   WAITVM(16) -> offsets ready, data flying; scatter runs under the flight;
//   barrier (vmcnt0 drain coincides with P0 arrival); then a barrier-free
//   plane-granular ring with 16-32 loads outstanding per wave, vmcnt never
//   drained to 0 mid-stream. One scatter per CU for the whole kernel.
__global__ __launch_bounds__(512, 2) void fused_bilinear_pool(
        const float* __restrict__ data,     // [B, C, H, W] fp32
        const float* __restrict__ offset,   // [B, 2, H, W] fp32
        const float* __restrict__ ts_ptr,   // scalar fp32
        float* __restrict__ out)            // [B, C] fp32
{
    const int blk  = blockIdx.x;            // 0..255
    const int b    = blk >> 3;              // 8 blocks per batch
    const int g    = blk & 7;               // 32-channel group within batch
    const int tid  = threadIdx.x;           // 0..511
    const int w    = tid >> 6;              // wave id 0..7
    const int lane = tid & 63;

    __shared__ float acc[HW];               // 16 KiB weight map

    // ts first: its compiler-emitted vmcnt(0) happens BEFORE any asm loads
    float ts = ts_ptr[0];
    ts = fminf(fmaxf(ts, 0.001f), 0.01f);

    // ---- zero the map (no vmem in flight across this barrier) ----
    #pragma unroll
    for (int z = 0; z < 8; ++z) acc[tid + z * 512] = 0.0f;
    __syncthreads();

    // ---- asm-pin: offsets (oldest), then plane P0's 16 data loads ----
    const float* off_y = offset + (size_t)b * 2 * HW + tid * 8;  // 8 pts/thread
    const float* off_x = off_y + HW;
    v4f dy4a, dy4b, dx4a, dx4b;
    asm volatile(
        "global_load_dwordx4 %0, %4, off\n\t"
        "global_load_dwordx4 %1, %4, off offset:16\n\t"
        "global_load_dwordx4 %2, %5, off\n\t"
        "global_load_dwordx4 %3, %5, off offset:16"
        : "=&v"(dy4a), "=&v"(dy4b), "=&v"(dx4a), "=&v"(dx4b)
        : "v"(off_y), "v"(off_x)
        : "memory");

    const int c0 = g * CPB;
    const float* p0 = data + ((size_t)b * CHAN + c0 + w) * HW + lane * 4;
    const float* p1 = p0 + 8 * HW;    // wave's planes: c0+w+8k, k=0..3
    const float* p2 = p0 + 16 * HW;
    const float* p3 = p0 + 24 * HW;

    v4f A0,A1,A2,A3,A4,A5,A6,A7,A8,A9,A10,A11,A12,A13,A14,A15;
    v4f B0,B1,B2,B3,B4,B5,B6,B7,B8,B9,B10,B11,B12,B13,B14,B15;

    GLOADP(A, p0);                          // 16 data loads in flight

    WAITVM(16);                             // offsets landed, data still flying

    // ---- scatter 8 contiguous points per thread, UNDER the data flight ----
    {
        const int i  = tid >> 3;            // (8*tid) >> 6
        const int j0 = (tid & 7) * 8;
        const float dys[8] = {dy4a.x, dy4a.y, dy4a.z, dy4a.w,
                              dy4b.x, dy4b.y, dy4b.z, dy4b.w};
        const float dxs[8] = {dx4a.x, dx4a.y, dx4a.z, dx4a.w,
                              dx4b.x, dx4b.y, dx4b.z, dx4b.w};
        #pragma unroll
        for (int e = 0; e < 8; ++e) {
            // reference eval order: clip(i + (ts*offset)*H, 0, H-1)
            float y = fminf(fmaxf((float)i        + ts * dys[e] * 64.0f, 0.0f), 63.0f);
            float x = fminf(fmaxf((float)(j0 + e) + ts * dxs[e] * 64.0f, 0.0f), 63.0f);
            int y0 = (int)floorf(y); y0 = min(max(y0, 0), HGT - 2);
            int x0 = (int)floorf(x); x0 = min(max(x0, 0), WID - 2);
            const float wy = y - (float)y0;
            const float wx = x - (float)x0;
            const int base = (y0 << 6) + x0;
            atomicAdd(&acc[base],           (1.0f - wy) * (1.0f - wx));
            atomicAdd(&acc[base + 1],       (1.0f - wy) * wx);
            atomicAdd(&acc[base + WID],     wy * (1.0f - wx));
            atomicAdd(&acc[base + WID + 1], wy * wx);
        }
    }
    __syncthreads();   // map ready; vmcnt(0) drain ~coincides with P0 arrival

    const float* hp0 = acc + lane * 4;          // map half 0 (this lane's cols)
    const float* hp1 = acc + 2048 + lane * 4;   // map half 1

    // ---- barrier-free plane ring: 16-32 loads outstanding, never vmcnt(0)
    //      mid-stream ----
    float r0, r1, r2, r3;

    GLOADP(B, p1);                 // issue P1 (16 out; P0 already in regs)
    DRAINP(A, hp0, hp1, r0);       // drain P0
    GLOADP(A, p2);                 // issue P2 (32 out)
    WAITVM(16);                    // P1 landed
    DRAINP(B, hp0, hp1, r1);       // drain P1
    GLOADP(B, p3);                 // issue P3 (32 out)
    WAITVM(16);                    // P2 landed
    DRAINP(A, hp0, hp1, r2);       // drain P2
    WAITVM(0);                     // P3 landed (end of stream)
    DRAINP(B, hp0, hp1, r3);       // drain P3

    // ---- 4 independent wave-64 shuffle-reduce chains (they pipeline) ----
    #pragma unroll
    for (int off = 32; off > 0; off >>= 1) {
        r0 += __shfl_down(r0, off, 64);
        r1 += __shfl_down(r1, off, 64);
        r2 += __shfl_down(r2, off, 64);
        r3 += __shfl_down(r3, off, 64);
    }

    if (lane == 0) {
        const float s = 1.0f / (float)HW;   // fold the mean
        float* ob = out + (b << 8) + c0 + w;
        ob[0]  = r0 * s;
        ob[8]  = r1 * s;
        ob[16] = r2 * s;
        ob[24] = r3 * s;
    }
}

extern "C" void kernel_launch(void* const* d_in, const int* in_sizes, int n_in,
                              void* d_out, int out_size, void* d_ws, size_t ws_size,
                              hipStream_t stream) {
    const float* data   = (const float*)d_in[0];  // fp32 [32,256,64,64]
    const float* offset = (const float*)d_in[1];  // fp32 [32,2,64,64]
    const float* ts     = (const float*)d_in[2];  // fp32 scalar

    float* out = (float*)d_out;                   // [32, 256] fp32
    (void)d_ws; (void)ws_size;                    // workspace intentionally unused

    fused_bilinear_pool<<<BATCH * GPB, 512, 0, stream>>>(data, offset, ts, out);
}

// Round 11
// 201.742 us; speedup vs baseline: 1.1945x; 1.0043x over previous
//
#include <hip/hip_runtime.h>
#include <stdint.h>

// Problem constants (fixed by setup_inputs): B=32, C=256, H=W=64
#define BATCH 32
#define CHAN  256
#define HGT   64
#define WID   64
#define HW    4096   // HGT*WID
#define GPB   8      // blocks per batch  -> grid = 256 = exactly 1 block/CU
#define CPB   32     // channels per block (4 per wave)

typedef float v4f __attribute__((ext_vector_type(4)));

// 4 pinned 16B loads = one quarter-plane chunk (4 KiB/wave).
// asm volatile: compiler cannot sink/split/shrink (R5/R8 post-mortem).
#define ISSUE4(B0,B1,B2,B3, P)                                        \
    asm volatile(                                                      \
        "global_load_dwordx4 %0, %4, off\n\t"                          \
        "global_load_dwordx4 %1, %4, off offset:1024\n\t"              \
        "global_load_dwordx4 %2, %4, off offset:2048\n\t"              \
        "global_load_dwordx4 %3, %4, off offset:3072"                  \
        : "=&v"(B0), "=&v"(B1), "=&v"(B2), "=&v"(B3)                   \
        : "v"(P)                                                       \
        : "memory")

// counted wait; sched_barrier(0) so dependent FMAs can't hoist above (rule #18)
#define WAITVM(N)                                                      \
    asm volatile("s_waitcnt vmcnt(" #N ")" ::: "memory");              \
    __builtin_amdgcn_sched_barrier(0)

#define FMA4(S, AV, DV)                                                \
    S = fmaf((AV).x, (DV).x, S); S = fmaf((AV).y, (DV).y, S);          \
    S = fmaf((AV).z, (DV).z, S); S = fmaf((AV).w, (DV).w, S)

// drain one 4-load chunk against one quarter of the LDS map
#define DRAIN4(B0,B1,B2,B3, HP, S)                                     \
    { const float4 a0_ = *reinterpret_cast<const float4*>((HP) + 0*256); FMA4(S, a0_, B0); \
      const float4 a1_ = *reinterpret_cast<const float4*>((HP) + 1*256); FMA4(S, a1_, B1); \
      const float4 a2_ = *reinterpret_cast<const float4*>((HP) + 2*256); FMA4(S, a2_, B2); \
      const float4 a3_ = *reinterpret_cast<const float4*>((HP) + 3*256); FMA4(S, a3_, B3); }

// Fused v7: R10's geometry + T3/T4-style 4-load-granular sliding window.
//   256 blocks (1/CU), 512 threads (8 waves), 4 planes/wave, scatter once
//   per block under plane-0's flight. Steady state: WAITVM(12) -> drain the
//   oldest 4-load chunk -> reissue 4. FIFO window is a CONSTANT 16 loads
//   per wave (never below 12 until the terminal drain) -- continuous
//   request stream instead of R10's bursty 16-load phases.
__global__ __launch_bounds__(512, 2) void fused_bilinear_pool(
        const float* __restrict__ data,     // [B, C, H, W] fp32
        const float* __restrict__ offset,   // [B, 2, H, W] fp32
        const float* __restrict__ ts_ptr,   // scalar fp32
        float* __restrict__ out)            // [B, C] fp32
{
    const int blk  = blockIdx.x;            // 0..255
    const int b    = blk >> 3;              // 8 blocks per batch
    const int g    = blk & 7;               // 32-channel group within batch
    const int tid  = threadIdx.x;           // 0..511
    const int w    = tid >> 6;              // wave id 0..7
    const int lane = tid & 63;

    __shared__ float acc[HW];               // 16 KiB weight map

    // ts first: its compiler-emitted vmcnt(0) happens BEFORE any asm loads
    float ts = ts_ptr[0];
    ts = fminf(fmaxf(ts, 0.001f), 0.01f);

    // ---- zero the map (no vmem in flight across this barrier) ----
    #pragma unroll
    for (int z = 0; z < 8; ++z) acc[tid + z * 512] = 0.0f;
    __syncthreads();

    // ---- asm-pin: offsets (oldest), then plane P0's 16 data loads ----
    const float* off_y = offset + (size_t)b * 2 * HW + tid * 8;  // 8 pts/thread
    const float* off_x = off_y + HW;
    v4f dy4a, dy4b, dx4a, dx4b;
    asm volatile(
        "global_load_dwordx4 %0, %4, off\n\t"
        "global_load_dwordx4 %1, %4, off offset:16\n\t"
        "global_load_dwordx4 %2, %5, off\n\t"
        "global_load_dwordx4 %3, %5, off offset:16"
        : "=&v"(dy4a), "=&v"(dy4b), "=&v"(dx4a), "=&v"(dx4b)
        : "v"(off_y), "v"(off_x)
        : "memory");

    const int c0 = g * CPB;
    const float* p0 = data + ((size_t)b * CHAN + c0 + w) * HW + lane * 4;
    const float* p1 = p0 + 8 * HW;    // wave's planes: c0+w+8k, k=0..3
    const float* p2 = p0 + 16 * HW;
    const float* p3 = p0 + 24 * HW;

    v4f A0,A1,A2,A3,A4,A5,A6,A7,A8,A9,A10,A11,A12,A13,A14,A15;
    v4f B0,B1,B2,B3,B4,B5,B6,B7,B8,B9,B10,B11,B12,B13,B14,B15;

    ISSUE4(A0,A1,A2,A3,     p0);            // plane0 quarter 0
    ISSUE4(A4,A5,A6,A7,     p0 + 1024);     // quarter 1
    ISSUE4(A8,A9,A10,A11,   p0 + 2048);     // quarter 2
    ISSUE4(A12,A13,A14,A15, p0 + 3072);     // quarter 3

    WAITVM(16);                             // offsets landed, data flying

    // ---- scatter 8 contiguous points per thread, UNDER the data flight ----
    {
        const int i  = tid >> 3;            // (8*tid) >> 6
        const int j0 = (tid & 7) * 8;
        const float dys[8] = {dy4a.x, dy4a.y, dy4a.z, dy4a.w,
                              dy4b.x, dy4b.y, dy4b.z, dy4b.w};
        const float dxs[8] = {dx4a.x, dx4a.y, dx4a.z, dx4a.w,
                              dx4b.x, dx4b.y, dx4b.z, dx4b.w};
        #pragma unroll
        for (int e = 0; e < 8; ++e) {
            // reference eval order: clip(i + (ts*offset)*H, 0, H-1)
            float y = fminf(fmaxf((float)i        + ts * dys[e] * 64.0f, 0.0f), 63.0f);
            float x = fminf(fmaxf((float)(j0 + e) + ts * dxs[e] * 64.0f, 0.0f), 63.0f);
            int y0 = (int)floorf(y); y0 = min(max(y0, 0), HGT - 2);
            int x0 = (int)floorf(x); x0 = min(max(x0, 0), WID - 2);
            const float wy = y - (float)y0;
            const float wx = x - (float)x0;
            const int base = (y0 << 6) + x0;
            atomicAdd(&acc[base],           (1.0f - wy) * (1.0f - wx));
            atomicAdd(&acc[base + 1],       (1.0f - wy) * wx);
            atomicAdd(&acc[base + WID],     wy * (1.0f - wx));
            atomicAdd(&acc[base + WID + 1], wy * wx);
        }
    }
    __syncthreads();   // vmcnt(0) drain ~coincides with P0 arrival; map ready

    // quarter bases of the map for this lane
    const float* hq0 = acc +    0 + lane * 4;
    const float* hq1 = acc + 1024 + lane * 4;
    const float* hq2 = acc + 2048 + lane * 4;
    const float* hq3 = acc + 3072 + lane * 4;

    // per-chunk accumulators (16 independent FMA chains)
    float r00=0.f,r01=0.f,r02=0.f,r03=0.f;
    float r10=0.f,r11=0.f,r12=0.f,r13=0.f;
    float r20=0.f,r21=0.f,r22=0.f,r23=0.f;
    float r30=0.f,r31=0.f,r32=0.f,r33=0.f;

    // ---- refill window with P1, then drain P0 (already landed) ----
    ISSUE4(B0,B1,B2,B3,     p1);
    ISSUE4(B4,B5,B6,B7,     p1 + 1024);
    ISSUE4(B8,B9,B10,B11,   p1 + 2048);
    ISSUE4(B12,B13,B14,B15, p1 + 3072);

    DRAIN4(A0,A1,A2,A3,     hq0, r00);
    DRAIN4(A4,A5,A6,A7,     hq1, r01);
    DRAIN4(A8,A9,A10,A11,   hq2, r02);
    DRAIN4(A12,A13,A14,A15, hq3, r03);

    // ---- steady: constant 16-load window, 4-granular ----
    WAITVM(12); DRAIN4(B0,B1,B2,B3,     hq0, r10); ISSUE4(A0,A1,A2,A3,     p2);
    WAITVM(12); DRAIN4(B4,B5,B6,B7,     hq1, r11); ISSUE4(A4,A5,A6,A7,     p2 + 1024);
    WAITVM(12); DRAIN4(B8,B9,B10,B11,   hq2, r12); ISSUE4(A8,A9,A10,A11,   p2 + 2048);
    WAITVM(12); DRAIN4(B12,B13,B14,B15, hq3, r13); ISSUE4(A12,A13,A14,A15, p2 + 3072);

    WAITVM(12); DRAIN4(A0,A1,A2,A3,     hq0, r20); ISSUE4(B0,B1,B2,B3,     p3);
    WAITVM(12); DRAIN4(A4,A5,A6,A7,     hq1, r21); ISSUE4(B4,B5,B6,B7,     p3 + 1024);
    WAITVM(12); DRAIN4(A8,A9,A10,A11,   hq2, r22); ISSUE4(B8,B9,B10,B11,   p3 + 2048);
    WAITVM(12); DRAIN4(A12,A13,A14,A15, hq3, r23); ISSUE4(B12,B13,B14,B15, p3 + 3072);

    // ---- terminal drain of P3 ----
    WAITVM(12); DRAIN4(B0,B1,B2,B3,     hq0, r30);
    WAITVM(8);  DRAIN4(B4,B5,B6,B7,     hq1, r31);
    WAITVM(4);  DRAIN4(B8,B9,B10,B11,   hq2, r32);
    WAITVM(0);  DRAIN4(B12,B13,B14,B15, hq3, r33);

    float r0 = (r00 + r01) + (r02 + r03);
    float r1 = (r10 + r11) + (r12 + r13);
    float r2 = (r20 + r21) + (r22 + r23);
    float r3 = (r30 + r31) + (r32 + r33);

    // ---- 4 independent wave-64 shuffle-reduce chains ----
    #pragma unroll
    for (int off = 32; off > 0; off >>= 1) {
        r0 += __shfl_down(r0, off, 64);
        r1 += __shfl_down(r1, off, 64);
        r2 += __shfl_down(r2, off, 64);
        r3 += __shfl_down(r3, off, 64);
    }

    if (lane == 0) {
        const float s = 1.0f / (float)HW;   // fold the mean
        float* ob = out + (b << 8) + c0 + w;
        ob[0]  = r0 * s;
        ob[8]  = r1 * s;
        ob[16] = r2 * s;
        ob[24] = r3 * s;
    }
}

extern "C" void kernel_launch(void* const* d_in, const int* in_sizes, int n_in,
                              void* d_out, int out_size, void* d_ws, size_t ws_size,
                              hipStream_t stream) {
    const float* data   = (const float*)d_in[0];  // fp32 [32,256,64,64]
    const float* offset = (const float*)d_in[1];  // fp32 [32,2,64,64]
    const float* ts     = (const float*)d_in[2];  // fp32 scalar

    float* out = (float*)d_out;                   // [32, 256] fp32
    (void)d_ws; (void)ws_size;                    // workspace intentionally unused

    fused_bilinear_pool<<<BATCH * GPB, 512, 0, stream>>>(data, offset, ts, out);
}